// Round 1
// baseline (270.824 us; speedup 1.0000x reference)
//
#include <hip/hip_runtime.h>
#include <math.h>

// Problem constants (from reference): B=8, S=128, V=32000, K=32.
constexpr int Bc = 8, Sc = 128, Vc = 32000, Kc = 32;
constexpr int NT = 512;                    // threads per block (8 waves)
constexpr int V4 = Vc / 4;                 // 8000 float4 per row
constexpr int ITERS = (V4 + NT - 1) / NT;  // 16
constexpr int NWAVES = NT / 64;            // 8

// One block per (b,s) row, row register-resident as 16 x float4 per thread.
// 512-thread blocks + VGPR cap 84 -> 6 waves/SIMD -> 3 blocks/CU, so block
// phases stagger and HBM sees mixed read/write traffic instead of aligned
// read-burst / write-burst phases (the round-0 theory for the 2.4 TB/s).
// Online softmax: exp + local sum happen BEFORE any barrier; a single
// (m,s)-merge reduction replaces the previous max-reduce + sum-reduce.
__global__ __launch_bounds__(NT, 6) void SR_knnModel_kernel(
    const float* __restrict__ logit,        // [B,S,V]
    const int*   __restrict__ optor_vals,   // [B,S,K]
    const float* __restrict__ optor_dists,  // [B,S,K]
    const int*   __restrict__ const_vals,   // [B,S,K]
    const float* __restrict__ const_dists,  // [B,S,K]
    const int*   __restrict__ prev_words,   // [B,S]
    const float* __restrict__ optor_lamda,  // [1]
    const float* __restrict__ const_lamda,  // [1]
    const float* __restrict__ optor_temp,   // [1]
    const float* __restrict__ const_temp,   // [1]
    float* __restrict__ out)                // [B,S,V]
{
    const int row = blockIdx.x;             // b*S + s
    const int t   = threadIdx.x;
    const size_t base = (size_t)row * Vc;
    const float4* __restrict__ xin  = (const float4*)(logit + base);
    float4* __restrict__       xout = (float4*)(out + base);

    // ---- Phase 1: load row into registers, thread-local max ----
    float4 r[ITERS];
    float lmax = -INFINITY;
#pragma unroll
    for (int i = 0; i < ITERS; ++i) {
        const int idx = t + i * NT;
        if (i < ITERS - 1 || idx < V4) {    // folds to `true` for i<15
            const float4 v = xin[idx];
            r[i] = v;
            lmax = fmaxf(lmax, fmaxf(fmaxf(v.x, v.y), fmaxf(v.z, v.w)));
        }
    }
    // Every thread has >= 15 full float4 iterations, so lmax is finite.

    // ---- Phase 2 (pre-barrier): exp(v - lmax) in-place, thread-local sum.
    // Runs as soon as this thread's own loads land; overlaps other waves'
    // load latency instead of being trapped between two barriers. ----
    float lsum = 0.f;
#pragma unroll
    for (int i = 0; i < ITERS; ++i) {
        const int idx = t + i * NT;
        if (i < ITERS - 1 || idx < V4) {
            float4 v = r[i];
            v.x = __expf(v.x - lmax);
            v.y = __expf(v.y - lmax);
            v.z = __expf(v.z - lmax);
            v.w = __expf(v.w - lmax);
            r[i] = v;
            lsum += (v.x + v.y) + (v.z + v.w);
        }
    }

    // Hoist uniform per-row scalars here so the s_loads hide under the
    // reduction below.
    const int pw = prev_words[row];
    const float ol = optor_lamda[0];
    const float cl = const_lamda[0];

    // ---- Single online (m,s) reduction: wave butterfly -> LDS -> merge ----
    float m = lmax, s = lsum;
#pragma unroll
    for (int off = 32; off > 0; off >>= 1) {
        const float om = __shfl_xor(m, off);
        const float os = __shfl_xor(s, off);
        const float M  = fmaxf(m, om);
        s = s * __expf(m - M) + os * __expf(om - M);
        m = M;
    }
    __shared__ float2 red[NWAVES];
    const int wave = t >> 6;
    if ((t & 63) == 0) red[wave] = make_float2(m, s);
    __syncthreads();
    float M = red[0].x, S = red[0].y;
#pragma unroll
    for (int w = 1; w < NWAVES; ++w) {
        const float2 p = red[w];
        const float nM = fmaxf(M, p.x);
        S = S * __expf(M - nM) + p.y * __expf(p.x - nM);
        M = nM;
    }

    // ---- per-row scalars (masks are mutually exclusive in practice, but we
    // implement the fully-general linear combination from the reference) ----
    const bool om_ = (pw <= 88) || (pw >= 91 && pw <= 291);
    const bool cm_ = (pw == 89) || (pw == 90) || (pw >= 292);
    const float omf = om_ ? 1.f : 0.f;
    const float cmf = cm_ ? 1.f : 0.f;
    const float cn = (1.f - ol) * omf + (1.f - cl) * cmf;   // coeff on nmt_prob
    // stored r[] = exp(v - lmax); true prob = r * exp(lmax - M) / S
    const float f = __expf(lmax - M) * (cn / S);

    // ---- Phase 3: scale + store ----
#pragma unroll
    for (int i = 0; i < ITERS; ++i) {
        const int idx = t + i * NT;
        if (i < ITERS - 1 || idx < V4) {
            float4 v = r[i];
            v.x *= f; v.y *= f; v.z *= f; v.w *= f;
            xout[idx] = v;
        }
    }
    __syncthreads();   // drains vmcnt -> bulk stores visible before atomics

    // ---- kNN scatter: wave0 lanes 0..31 = optor, wave1 lanes 0..31 = const.
    // softmax over K=32 of -d/temp, then atomicAdd(lam*mask*w) at val positions.
    if (t < 32 || (t >= 64 && t < 96)) {
        const bool is_opt = (t < 32);
        const float scale = is_opt ? ol * omf : cl * cmf;
        if (scale != 0.f) {                 // uniform within each 32-lane group
            const int k = t & 31;
            const int*   vals  = is_opt ? optor_vals  : const_vals;
            const float* dists = is_opt ? optor_dists : const_dists;
            const float  temp  = is_opt ? optor_temp[0] : const_temp[0];
            const float sc = -dists[row * Kc + k] / temp;
            float mm = sc;
#pragma unroll
            for (int off = 16; off > 0; off >>= 1)
                mm = fmaxf(mm, __shfl_xor(mm, off));
            const float e = __expf(sc - mm);
            float sm = e;
#pragma unroll
            for (int off = 16; off > 0; off >>= 1)
                sm += __shfl_xor(sm, off);
            const float w = e / sm;
            atomicAdd(out + base + vals[row * Kc + k], scale * w);
        }
    }
}

extern "C" void kernel_launch(void* const* d_in, const int* in_sizes, int n_in,
                              void* d_out, int out_size, void* d_ws, size_t ws_size,
                              hipStream_t stream) {
    const float* logit       = (const float*)d_in[0];
    const int*   optor_vals  = (const int*)  d_in[1];
    const float* optor_dists = (const float*)d_in[2];
    const int*   const_vals  = (const int*)  d_in[3];
    const float* const_dists = (const float*)d_in[4];
    const int*   prev_words  = (const int*)  d_in[5];
    const float* optor_lamda = (const float*)d_in[6];
    const float* const_lamda = (const float*)d_in[7];
    const float* optor_temp  = (const float*)d_in[8];
    const float* const_temp  = (const float*)d_in[9];
    float* out = (float*)d_out;

    SR_knnModel_kernel<<<Bc * Sc, NT, 0, stream>>>(
        logit, optor_vals, optor_dists, const_vals, const_dists, prev_words,
        optor_lamda, const_lamda, optor_temp, const_temp, out);
}

// Round 2
// 249.797 us; speedup vs baseline: 1.0842x; 1.0842x over previous
//
#include <hip/hip_runtime.h>
#include <math.h>

// Problem constants (from reference): B=8, S=128, V=32000, K=32.
constexpr int Bc = 8, Sc = 128, Vc = 32000, Kc = 32;
constexpr int NT = 1024;                   // threads per block (16 waves)
constexpr int V4 = Vc / 4;                 // 8000 float4 per row
constexpr int ITERS = (V4 + NT - 1) / NT;  // 8
constexpr int NWAVES = NT / 64;            // 16

// clang vector type so __builtin_nontemporal_store emits global_store_dwordx4 nt
typedef float vfloat4 __attribute__((ext_vector_type(4)));

// One block per (b,s) row, row register-resident as 8 x float4 per thread
// (proven no-spill geometry: 36-44 VGPR, 2 blocks/CU).
// Round-2 changes vs round-0:
//  * exp() uses the THREAD-local max and runs BEFORE any barrier, so the
//    32000 transcendentals overlap other waves' load latency instead of
//    sitting serialized between a max-reduce and a sum-reduce.
//  * single fused (m,s) online reduction (one barrier instead of two).
//  * bulk output stores are non-temporal: output is written once and never
//    re-read, so don't let it evict the L3-resident input.
__global__ __launch_bounds__(NT) void SR_knnModel_kernel(
    const float* __restrict__ logit,        // [B,S,V]
    const int*   __restrict__ optor_vals,   // [B,S,K]
    const float* __restrict__ optor_dists,  // [B,S,K]
    const int*   __restrict__ const_vals,   // [B,S,K]
    const float* __restrict__ const_dists,  // [B,S,K]
    const int*   __restrict__ prev_words,   // [B,S]
    const float* __restrict__ optor_lamda,  // [1]
    const float* __restrict__ const_lamda,  // [1]
    const float* __restrict__ optor_temp,   // [1]
    const float* __restrict__ const_temp,   // [1]
    float* __restrict__ out)                // [B,S,V]
{
    const int row = blockIdx.x;             // b*S + s
    const int t   = threadIdx.x;
    const size_t base = (size_t)row * Vc;
    const float4* __restrict__ xin  = (const float4*)(logit + base);
    float* __restrict__        orow = out + base;

    // ---- Phase 1: load row into registers, thread-local max ----
    float4 r[ITERS];
    float lmax = -INFINITY;
#pragma unroll
    for (int i = 0; i < ITERS; ++i) {
        const int idx = t + i * NT;
        if (i < ITERS - 1 || idx < V4) {    // folds to `true` for i<7
            const float4 v = xin[idx];
            r[i] = v;
            lmax = fmaxf(lmax, fmaxf(fmaxf(v.x, v.y), fmaxf(v.z, v.w)));
        }
    }
    // Every thread has 7 full float4 iterations, so lmax is finite.

    // ---- Phase 2 (pre-barrier): exp(v - lmax) in-place, thread-local sum.
    // lmax is the THREAD max; rescale to the block max happens once per
    // thread at the end (f *= exp(lmax - M)). Inputs are N(0,1) logits, so
    // exp(v - lmax) is comfortably bounded in fp32. ----
    float lsum = 0.f;
#pragma unroll
    for (int i = 0; i < ITERS; ++i) {
        const int idx = t + i * NT;
        if (i < ITERS - 1 || idx < V4) {
            float4 v = r[i];
            v.x = __expf(v.x - lmax);
            v.y = __expf(v.y - lmax);
            v.z = __expf(v.z - lmax);
            v.w = __expf(v.w - lmax);
            r[i] = v;
            lsum += (v.x + v.y) + (v.z + v.w);
        }
    }

    // Hoist uniform per-row scalars here so the loads hide under the
    // reduction below.
    const int pw = prev_words[row];
    const float ol = optor_lamda[0];
    const float cl = const_lamda[0];

    // ---- Single online (m,s) reduction: wave butterfly -> LDS -> merge ----
    float m = lmax, s = lsum;
#pragma unroll
    for (int off = 32; off > 0; off >>= 1) {
        const float om = __shfl_xor(m, off);
        const float os = __shfl_xor(s, off);
        const float M2 = fmaxf(m, om);
        s = s * __expf(m - M2) + os * __expf(om - M2);
        m = M2;
    }
    __shared__ float2 red[NWAVES];
    const int wave = t >> 6;
    if ((t & 63) == 0) red[wave] = make_float2(m, s);
    __syncthreads();
    float M = red[0].x, S = red[0].y;
#pragma unroll
    for (int w = 1; w < NWAVES; ++w) {
        const float2 p = red[w];
        const float nM = fmaxf(M, p.x);
        S = S * __expf(M - nM) + p.y * __expf(p.x - nM);
        M = nM;
    }

    // ---- per-row scalars (masks are mutually exclusive in practice, but we
    // implement the fully-general linear combination from the reference) ----
    const bool om_ = (pw <= 88) || (pw >= 91 && pw <= 291);
    const bool cm_ = (pw == 89) || (pw == 90) || (pw >= 292);
    const float omf = om_ ? 1.f : 0.f;
    const float cmf = cm_ ? 1.f : 0.f;
    const float cn = (1.f - ol) * omf + (1.f - cl) * cmf;   // coeff on nmt_prob
    // stored r[] = exp(v - lmax_thread); true prob = r * exp(lmax - M) / S
    const float f = __expf(lmax - M) * (cn / S);

    // ---- Phase 3: scale + non-temporal store ----
#pragma unroll
    for (int i = 0; i < ITERS; ++i) {
        const int idx = t + i * NT;
        if (i < ITERS - 1 || idx < V4) {
            const float4 v = r[i];
            vfloat4 o;
            o.x = v.x * f; o.y = v.y * f; o.z = v.z * f; o.w = v.w * f;
            __builtin_nontemporal_store(o, (vfloat4*)orow + idx);
        }
    }
    __syncthreads();   // drains vmcnt -> bulk stores visible before atomics

    // ---- kNN scatter: wave0 lanes 0..31 = optor, wave1 lanes 0..31 = const.
    // softmax over K=32 of -d/temp, then atomicAdd(lam*mask*w) at val positions.
    if (t < 32 || (t >= 64 && t < 96)) {
        const bool is_opt = (t < 32);
        const float scale = is_opt ? ol * omf : cl * cmf;
        if (scale != 0.f) {                 // uniform within each 32-lane group
            const int k = t & 31;
            const int*   vals  = is_opt ? optor_vals  : const_vals;
            const float* dists = is_opt ? optor_dists : const_dists;
            const float  temp  = is_opt ? optor_temp[0] : const_temp[0];
            const float sc = -dists[row * Kc + k] / temp;
            float mm = sc;
#pragma unroll
            for (int off = 16; off > 0; off >>= 1)
                mm = fmaxf(mm, __shfl_xor(mm, off));
            const float e = __expf(sc - mm);
            float sm = e;
#pragma unroll
            for (int off = 16; off > 0; off >>= 1)
                sm += __shfl_xor(sm, off);
            const float w = e / sm;
            atomicAdd(out + base + vals[row * Kc + k], scale * w);
        }
    }
}

extern "C" void kernel_launch(void* const* d_in, const int* in_sizes, int n_in,
                              void* d_out, int out_size, void* d_ws, size_t ws_size,
                              hipStream_t stream) {
    const float* logit       = (const float*)d_in[0];
    const int*   optor_vals  = (const int*)  d_in[1];
    const float* optor_dists = (const float*)d_in[2];
    const int*   const_vals  = (const int*)  d_in[3];
    const float* const_dists = (const float*)d_in[4];
    const int*   prev_words  = (const int*)  d_in[5];
    const float* optor_lamda = (const float*)d_in[6];
    const float* const_lamda = (const float*)d_in[7];
    const float* optor_temp  = (const float*)d_in[8];
    const float* const_temp  = (const float*)d_in[9];
    float* out = (float*)d_out;

    SR_knnModel_kernel<<<Bc * Sc, NT, 0, stream>>>(
        logit, optor_vals, optor_dists, const_vals, const_dists, prev_words,
        optor_lamda, const_lamda, optor_temp, const_temp, out);
}